// Round 1
// baseline (458.191 us; speedup 1.0000x reference)
//
#include <hip/hip_runtime.h>

// ---------------- weight blob layout (float offsets in d_ws) ----------------
#define OFF_CW1   0      // [16][16]: row f = [Wp1[f][0..7] | Ws1[f][0..7]]
#define OFF_BP1   256    // [8]
#define OFF_BC1   264    // [8]
#define OFF_WN1   272    // [8][8]
#define OFF_CW2   336    // Wp2 [8][8]
#define OFF_BP2   400    // [8]
#define OFF_A     408    // (Ws2@W1[0:8])/32  [8][64]
#define OFF_C     920    // (Wn2@W1[0:8])/32  [8][64]
#define OFF_W1B   1432   // W1[8:24] [16][64]
#define OFF_BF1P  2456   // bf1 + bc2@W1[0:8]  [64]
#define OFF_W2    2520   // [64][64]
#define OFF_BF2   6616
#define OFF_W3    6680   // [64][64]
#define OFF_BF3   10776
#define OFF_W4    10840  // [64][4]
#define OFF_BF4   11096
#define RES_OFF   16384  // res buffer starts at 64KB into d_ws; [B][16] floats

__device__ __forceinline__ float fast_tanh(float v) {
  v = fminf(fmaxf(v, -10.f), 10.f);
  float e = exp2f(v * 2.8853900817779268f);          // e^(2v)
  return 1.f - 2.f * __builtin_amdgcn_rcpf(e + 1.f); // (e-1)/(e+1)
}

// ---------------- K0: fold weights into blob (1 block) ----------------
__global__ void setup_blob(const float* __restrict__ Wp1, const float* __restrict__ bp1,
                           const float* __restrict__ Ws1, const float* __restrict__ Wn1,
                           const float* __restrict__ bc1,
                           const float* __restrict__ Wp2, const float* __restrict__ bp2,
                           const float* __restrict__ Ws2, const float* __restrict__ Wn2,
                           const float* __restrict__ bc2,
                           const float* __restrict__ W1, const float* __restrict__ bf1,
                           const float* __restrict__ W2, const float* __restrict__ bf2,
                           const float* __restrict__ W3, const float* __restrict__ bf3,
                           const float* __restrict__ W4, const float* __restrict__ bf4,
                           float* __restrict__ blob) {
  const int t = threadIdx.x; // 256 threads
  if (t < 128) { int f = t >> 3, g = t & 7;
    blob[OFF_CW1 + f*16 + g]     = Wp1[f*8 + g];
    blob[OFF_CW1 + f*16 + 8 + g] = Ws1[f*8 + g];
  }
  if (t < 8) { blob[OFF_BP1+t] = bp1[t]; blob[OFF_BC1+t] = bc1[t]; blob[OFF_BP2+t] = bp2[t]; }
  if (t < 64) { blob[OFF_WN1+t] = Wn1[t]; blob[OFF_CW2+t] = Wp2[t]; }
  if (t < 4)  { blob[OFF_BF4+t] = bf4[t]; }
  blob[OFF_W4 + t] = W4[t]; // 256 elements
  if (t < 64) {
    const int o = t;
    float accB = bf1[o];
    for (int k = 0; k < 8; k++) accB += bc2[k] * W1[k*64 + o];
    blob[OFF_BF1P + o] = accB;
    for (int j = 0; j < 8; j++) {
      float a = 0.f, c = 0.f;
      for (int k = 0; k < 8; k++) {
        a += Ws2[j*8 + k] * W1[k*64 + o];
        c += Wn2[j*8 + k] * W1[k*64 + o];
      }
      blob[OFF_A + j*64 + o] = a * (1.f/32.f);
      blob[OFF_C + j*64 + o] = c * (1.f/32.f);
    }
    for (int i = 0; i < 16; i++) blob[OFF_W1B + i*64 + o] = W1[(8+i)*64 + o];
    blob[OFF_BF2 + o] = bf2[o];
    blob[OFF_BF3 + o] = bf3[o];
    for (int k = 0; k < 64; k++) {
      blob[OFF_W2 + k*64 + o] = W2[k*64 + o];
      blob[OFF_W3 + k*64 + o] = W3[k*64 + o];
    }
  }
}

// ---------------- K1: conv1+conv2+pool -> res[B][16] = {sumh[8], aggs[8]} ----
// 2 batches per wave: lane = (s = lane>>5 -> batch in pair, n = lane&31 -> node)
__global__ __launch_bounds__(256) void conv_kernel(const float* __restrict__ x,
                                                   const float* __restrict__ wb,
                                                   float* __restrict__ res) {
  const int lane = threadIdx.x & 63;
  const int wid  = blockIdx.x * (blockDim.x >> 6) + (threadIdx.x >> 6);
  const int nw   = gridDim.x * (blockDim.x >> 6);
  const int s = lane >> 5, n = lane & 31;

  for (int pair = wid; pair < 32768; pair += nw) {
    const int b = pair * 2 + s;
    const float4* xp = (const float4*)(x + ((size_t)b * 32 + n) * 16);
    float4 a0 = xp[0], a1 = xp[1], a2 = xp[2], a3 = xp[3];
    float xr[16] = {a0.x,a0.y,a0.z,a0.w, a1.x,a1.y,a1.z,a1.w,
                    a2.x,a2.y,a2.z,a2.w, a3.x,a3.y,a3.z,a3.w};
    // conv1: m = relu(x@Wp1+bp1), sp = x@Ws1 (+bc1)
    float m[8], sp[8];
    #pragma unroll
    for (int g = 0; g < 8; g++) { m[g] = wb[OFF_BP1+g]; sp[g] = wb[OFF_BC1+g]; }
    #pragma unroll
    for (int f = 0; f < 16; f++) {
      #pragma unroll
      for (int g = 0; g < 8; g++) {
        m[g]  = fmaf(xr[f], wb[OFF_CW1 + f*16 + g],     m[g]);
        sp[g] = fmaf(xr[f], wb[OFF_CW1 + f*16 + 8 + g], sp[g]);
      }
    }
    #pragma unroll
    for (int g = 0; g < 8; g++) m[g] = fmaxf(m[g], 0.f);

    // agg: node0 -> max over leaves (zero lane-0, relu>=0); leaves -> m0
    float agg[8];
    #pragma unroll
    for (int g = 0; g < 8; g++) {
      float t = (n == 0) ? 0.f : m[g];
      t = fmaxf(t, __shfl_xor(t, 1, 32));
      t = fmaxf(t, __shfl_xor(t, 2, 32));
      t = fmaxf(t, __shfl_xor(t, 4, 32));
      t = fmaxf(t, __shfl_xor(t, 8, 32));
      t = fmaxf(t, __shfl_xor(t, 16, 32));
      float m0 = __shfl(m[g], 0, 32);
      agg[g] = (n == 0) ? t : m0;
    }
    #pragma unroll
    for (int j = 0; j < 8; j++)
      #pragma unroll
      for (int g = 0; g < 8; g++)
        sp[g] = fmaf(agg[j], wb[OFF_WN1 + j*8 + g], sp[g]);

    float h[8];
    #pragma unroll
    for (int g = 0; g < 8; g++) h[g] = fast_tanh(sp[g]);

    // conv2 pool-proj: m2 = relu(h@Wp2+bp2)
    float m2[8];
    #pragma unroll
    for (int g = 0; g < 8; g++) m2[g] = wb[OFF_BP2+g];
    #pragma unroll
    for (int j = 0; j < 8; j++)
      #pragma unroll
      for (int g = 0; g < 8; g++)
        m2[g] = fmaf(h[j], wb[OFF_CW2 + j*8 + g], m2[g]);
    #pragma unroll
    for (int g = 0; g < 8; g++) m2[g] = fmaxf(m2[g], 0.f);

    // reductions: sumh[g] = sum_n h; aggs[g] = maxleaf(m2) + 31*m2_node0
    float outv[16];
    #pragma unroll
    for (int g = 0; g < 8; g++) {
      float t = (n == 0) ? 0.f : m2[g];
      t = fmaxf(t, __shfl_xor(t, 1, 32));
      t = fmaxf(t, __shfl_xor(t, 2, 32));
      t = fmaxf(t, __shfl_xor(t, 4, 32));
      t = fmaxf(t, __shfl_xor(t, 8, 32));
      t = fmaxf(t, __shfl_xor(t, 16, 32));
      float m20 = __shfl(m2[g], 0, 32);
      outv[8+g] = t + 31.f * m20;
      float sh = h[g];
      sh += __shfl_xor(sh, 1, 32);
      sh += __shfl_xor(sh, 2, 32);
      sh += __shfl_xor(sh, 4, 32);
      sh += __shfl_xor(sh, 8, 32);
      sh += __shfl_xor(sh, 16, 32);
      outv[g] = sh;
    }
    if (n == 0) {
      float4* rp = (float4*)(res + (size_t)b * 16);
      rp[0] = make_float4(outv[0], outv[1], outv[2], outv[3]);
      rp[1] = make_float4(outv[4], outv[5], outv[6], outv[7]);
      rp[2] = make_float4(outv[8], outv[9], outv[10], outv[11]);
      rp[3] = make_float4(outv[12], outv[13], outv[14], outv[15]);
    }
  }
}

// ---------------- K2: MLP, one batch per thread, SGPR weight stream ---------
__global__ __launch_bounds__(256) void mlp_kernel(const float* __restrict__ res,
                                                  const float* __restrict__ obs,
                                                  const float* __restrict__ wb,
                                                  float* __restrict__ out) {
  const int t = blockIdx.x * 256 + threadIdx.x; // 0..65535
  const float4* rp = (const float4*)(res + (size_t)t * 16);
  float4 r0 = rp[0], r1 = rp[1], r2 = rp[2], r3 = rp[3];
  const float4* op = (const float4*)(obs + (size_t)t * 16);
  float4 o0 = op[0], o1 = op[1], o2 = op[2], o3 = op[3];
  float rm[8] = {r0.x,r0.y,r0.z,r0.w, r1.x,r1.y,r1.z,r1.w};
  float ag[8] = {r2.x,r2.y,r2.z,r2.w, r3.x,r3.y,r3.z,r3.w};
  float ob[16] = {o0.x,o0.y,o0.z,o0.w, o1.x,o1.y,o1.z,o1.w,
                  o2.x,o2.y,o2.z,o2.w, o3.x,o3.y,o3.z,o3.w};

  float h1[64];
  #pragma unroll
  for (int o = 0; o < 64; o++) h1[o] = wb[OFF_BF1P + o];
  #pragma unroll
  for (int j = 0; j < 8; j++)
    #pragma unroll
    for (int o = 0; o < 64; o++) h1[o] = fmaf(rm[j], wb[OFF_A + j*64 + o], h1[o]);
  #pragma unroll
  for (int j = 0; j < 8; j++)
    #pragma unroll
    for (int o = 0; o < 64; o++) h1[o] = fmaf(ag[j], wb[OFF_C + j*64 + o], h1[o]);
  #pragma unroll
  for (int i = 0; i < 16; i++)
    #pragma unroll
    for (int o = 0; o < 64; o++) h1[o] = fmaf(ob[i], wb[OFF_W1B + i*64 + o], h1[o]);
  #pragma unroll
  for (int o = 0; o < 64; o++) h1[o] = fmaxf(h1[o], 0.f);

  float h2[64];
  #pragma unroll
  for (int o = 0; o < 64; o++) h2[o] = wb[OFF_BF2 + o];
  #pragma unroll
  for (int k = 0; k < 64; k++)
    #pragma unroll
    for (int o = 0; o < 64; o++) h2[o] = fmaf(h1[k], wb[OFF_W2 + k*64 + o], h2[o]);
  #pragma unroll
  for (int o = 0; o < 64; o++) h2[o] = fmaxf(h2[o], 0.f);

  // h3 reuses h1 storage
  #pragma unroll
  for (int o = 0; o < 64; o++) h1[o] = wb[OFF_BF3 + o];
  #pragma unroll
  for (int k = 0; k < 64; k++)
    #pragma unroll
    for (int o = 0; o < 64; o++) h1[o] = fmaf(h2[k], wb[OFF_W3 + k*64 + o], h1[o]);
  #pragma unroll
  for (int o = 0; o < 64; o++) h1[o] = fmaxf(h1[o], 0.f);

  float o4[4];
  #pragma unroll
  for (int d = 0; d < 4; d++) o4[d] = wb[OFF_BF4 + d];
  #pragma unroll
  for (int k = 0; k < 64; k++)
    #pragma unroll
    for (int d = 0; d < 4; d++) o4[d] = fmaf(h1[k], wb[OFF_W4 + k*4 + d], o4[d]);
  #pragma unroll
  for (int d = 0; d < 4; d++) o4[d] = fast_tanh(o4[d]);
  ((float4*)out)[t] = make_float4(o4[0], o4[1], o4[2], o4[3]);
}

extern "C" void kernel_launch(void* const* d_in, const int* in_sizes, int n_in,
                              void* d_out, int out_size, void* d_ws, size_t ws_size,
                              hipStream_t stream) {
  const float* x   = (const float*)d_in[0];
  const float* obs = (const float*)d_in[1];
  // d_in[2..4] = src/dst/node_seg: fixed star graph, structure exploited directly
  const float* Wp1 = (const float*)d_in[5];
  const float* bp1 = (const float*)d_in[6];
  const float* Ws1 = (const float*)d_in[7];
  const float* Wn1 = (const float*)d_in[8];
  const float* bc1 = (const float*)d_in[9];
  const float* Wp2 = (const float*)d_in[10];
  const float* bp2 = (const float*)d_in[11];
  const float* Ws2 = (const float*)d_in[12];
  const float* Wn2 = (const float*)d_in[13];
  const float* bc2 = (const float*)d_in[14];
  const float* W1  = (const float*)d_in[15];
  const float* bf1 = (const float*)d_in[16];
  const float* W2  = (const float*)d_in[17];
  const float* bf2 = (const float*)d_in[18];
  const float* W3  = (const float*)d_in[19];
  const float* bf3 = (const float*)d_in[20];
  const float* W4  = (const float*)d_in[21];
  const float* bf4 = (const float*)d_in[22];

  float* blob = (float*)d_ws;
  float* res  = (float*)d_ws + RES_OFF;
  float* out  = (float*)d_out;

  hipLaunchKernelGGL(setup_blob, dim3(1), dim3(256), 0, stream,
                     Wp1, bp1, Ws1, Wn1, bc1, Wp2, bp2, Ws2, Wn2, bc2,
                     W1, bf1, W2, bf2, W3, bf3, W4, bf4, blob);
  hipLaunchKernelGGL(conv_kernel, dim3(2048), dim3(256), 0, stream, x, blob, res);
  hipLaunchKernelGGL(mlp_kernel, dim3(256), dim3(256), 0, stream, res, obs, blob, out);
}

// Round 2
// 283.074 us; speedup vs baseline: 1.6186x; 1.6186x over previous
//
#include <hip/hip_runtime.h>

// ---------------- weight blob layout (float offsets in d_ws) ----------------
#define OFF_CW1   0      // [16][16]: row f = [Wp1[f][0..7] | Ws1[f][0..7]]
#define OFF_BP1   256    // [8]
#define OFF_BC1   264    // [8]
#define OFF_WN1   272    // [8][8]
#define OFF_CW2   336    // Wp2 [8][8]
#define OFF_BP2   400    // [8]
#define OFF_A     408    // (Ws2@W1[0:8])/32  [8][64]
#define OFF_C     920    // (Wn2@W1[0:8])/32  [8][64]
#define OFF_W1B   1432   // W1[8:24] [16][64]
#define OFF_BF1P  2456   // bf1 + bc2@W1[0:8]  [64]
#define OFF_W2    2520   // [64][64]
#define OFF_BF2   6616
#define OFF_W3    6680   // [64][64]
#define OFF_BF3   10776
#define OFF_W4    10840  // [64][4]
#define OFF_BF4   11096
#define RES_OFF   16384  // res buffer at 64KB into d_ws; [B][16] floats

__device__ __forceinline__ float fast_tanh(float v) {
  v = fminf(fmaxf(v, -10.f), 10.f);
  float e = exp2f(v * 2.8853900817779268f);          // e^(2v)
  return 1.f - 2.f * __builtin_amdgcn_rcpf(e + 1.f); // (e-1)/(e+1)
}

// ds_swizzle BitMode: new_lane = ((lane&and)|or)^xor within each 32-lane group.
// offset = (xor<<10)|(or<<5)|and. One DS instr, zero VALU index math.
template<int PAT>
__device__ __forceinline__ float swzf(float v) {
  return __int_as_float(__builtin_amdgcn_ds_swizzle(__float_as_int(v), PAT));
}
__device__ __forceinline__ float bfly_max32(float t) {
  t = fmaxf(t, swzf<0x041F>(t)); // xor 1
  t = fmaxf(t, swzf<0x081F>(t)); // xor 2
  t = fmaxf(t, swzf<0x101F>(t)); // xor 4
  t = fmaxf(t, swzf<0x201F>(t)); // xor 8
  t = fmaxf(t, swzf<0x401F>(t)); // xor 16
  return t;
}
__device__ __forceinline__ float bfly_sum32(float t) {
  t += swzf<0x041F>(t);
  t += swzf<0x081F>(t);
  t += swzf<0x101F>(t);
  t += swzf<0x201F>(t);
  t += swzf<0x401F>(t);
  return t;
}
__device__ __forceinline__ float bcast0_32(float t) { return swzf<0x0000>(t); }

// ---------------- K0: fold weights into blob (1 block) ----------------
__global__ void setup_blob(const float* __restrict__ Wp1, const float* __restrict__ bp1,
                           const float* __restrict__ Ws1, const float* __restrict__ Wn1,
                           const float* __restrict__ bc1,
                           const float* __restrict__ Wp2, const float* __restrict__ bp2,
                           const float* __restrict__ Ws2, const float* __restrict__ Wn2,
                           const float* __restrict__ bc2,
                           const float* __restrict__ W1, const float* __restrict__ bf1,
                           const float* __restrict__ W2, const float* __restrict__ bf2,
                           const float* __restrict__ W3, const float* __restrict__ bf3,
                           const float* __restrict__ W4, const float* __restrict__ bf4,
                           float* __restrict__ blob) {
  const int t = threadIdx.x; // 256 threads
  if (t < 128) { int f = t >> 3, g = t & 7;
    blob[OFF_CW1 + f*16 + g]     = Wp1[f*8 + g];
    blob[OFF_CW1 + f*16 + 8 + g] = Ws1[f*8 + g];
  }
  if (t < 8) { blob[OFF_BP1+t] = bp1[t]; blob[OFF_BC1+t] = bc1[t]; blob[OFF_BP2+t] = bp2[t]; }
  if (t < 64) { blob[OFF_WN1+t] = Wn1[t]; blob[OFF_CW2+t] = Wp2[t]; }
  if (t < 4)  { blob[OFF_BF4+t] = bf4[t]; }
  blob[OFF_W4 + t] = W4[t]; // 256 elements
  // parallel big copies
  for (int idx = t; idx < 4096; idx += 256) {
    blob[OFF_W2 + idx] = W2[idx];
    blob[OFF_W3 + idx] = W3[idx];
  }
  for (int idx = t; idx < 1024; idx += 256) blob[OFF_W1B + idx] = W1[512 + idx];
  if (t < 64) {
    const int o = t;
    float accB = bf1[o];
    for (int k = 0; k < 8; k++) accB += bc2[k] * W1[k*64 + o];
    blob[OFF_BF1P + o] = accB;
    for (int j = 0; j < 8; j++) {
      float a = 0.f, c = 0.f;
      for (int k = 0; k < 8; k++) {
        a += Ws2[j*8 + k] * W1[k*64 + o];
        c += Wn2[j*8 + k] * W1[k*64 + o];
      }
      blob[OFF_A + j*64 + o] = a * (1.f/32.f);
      blob[OFF_C + j*64 + o] = c * (1.f/32.f);
    }
    blob[OFF_BF2 + o] = bf2[o];
    blob[OFF_BF3 + o] = bf3[o];
  }
}

// ---------------- K1: conv1+conv2+pool -> res[B][16] = {sumh[8], aggs[8]} ----
// One batch-pair per wave, NO loop (minimal live ranges, no spills).
// lane = (s = lane>>5 -> batch in pair, n = lane&31 -> node)
__global__ __launch_bounds__(256, 4) void conv_kernel(const float* __restrict__ x,
                                                      const float* __restrict__ wb,
                                                      float* __restrict__ res) {
  const int lane = threadIdx.x & 63;
  const int pair = blockIdx.x * 4 + (threadIdx.x >> 6);
  const int s = lane >> 5, n = lane & 31;
  const int b = pair * 2 + s;

  const float4* xp = (const float4*)(x + ((size_t)b * 32 + n) * 16);
  float4 a0 = xp[0], a1 = xp[1], a2 = xp[2], a3 = xp[3];
  float xr[16] = {a0.x,a0.y,a0.z,a0.w, a1.x,a1.y,a1.z,a1.w,
                  a2.x,a2.y,a2.z,a2.w, a3.x,a3.y,a3.z,a3.w};
  // conv1: m = relu(x@Wp1+bp1), sp = x@Ws1 (+bc1)
  float m[8], sp[8];
  #pragma unroll
  for (int g = 0; g < 8; g++) { m[g] = wb[OFF_BP1+g]; sp[g] = wb[OFF_BC1+g]; }
  #pragma unroll
  for (int f = 0; f < 16; f++) {
    #pragma unroll
    for (int g = 0; g < 8; g++) {
      m[g]  = fmaf(xr[f], wb[OFF_CW1 + f*16 + g],     m[g]);
      sp[g] = fmaf(xr[f], wb[OFF_CW1 + f*16 + 8 + g], sp[g]);
    }
  }
  #pragma unroll
  for (int g = 0; g < 8; g++) m[g] = fmaxf(m[g], 0.f);

  // agg: node0 -> max over leaves (zero lane-0 contribution; relu>=0); leaves -> m0
  float agg[8];
  #pragma unroll
  for (int g = 0; g < 8; g++) {
    float t = (n == 0) ? 0.f : m[g];
    t = bfly_max32(t);
    float m0 = bcast0_32(m[g]);
    agg[g] = (n == 0) ? t : m0;
  }
  #pragma unroll
  for (int j = 0; j < 8; j++)
    #pragma unroll
    for (int g = 0; g < 8; g++)
      sp[g] = fmaf(agg[j], wb[OFF_WN1 + j*8 + g], sp[g]);

  float h[8];
  #pragma unroll
  for (int g = 0; g < 8; g++) h[g] = fast_tanh(sp[g]);

  // conv2 pool-proj: m2 = relu(h@Wp2+bp2)
  float m2[8];
  #pragma unroll
  for (int g = 0; g < 8; g++) m2[g] = wb[OFF_BP2+g];
  #pragma unroll
  for (int j = 0; j < 8; j++)
    #pragma unroll
    for (int g = 0; g < 8; g++)
      m2[g] = fmaf(h[j], wb[OFF_CW2 + j*8 + g], m2[g]);
  #pragma unroll
  for (int g = 0; g < 8; g++) m2[g] = fmaxf(m2[g], 0.f);

  // reductions: sumh[g] = sum_n h; aggs[g] = maxleaf(m2) + 31*m2_node0
  float outv[16];
  #pragma unroll
  for (int g = 0; g < 8; g++) {
    float t = (n == 0) ? 0.f : m2[g];
    t = bfly_max32(t);
    float m20 = bcast0_32(m2[g]);
    outv[8+g] = t + 31.f * m20;
    outv[g] = bfly_sum32(h[g]);
  }
  if (n == 0) {
    float4* rp = (float4*)(res + (size_t)b * 16);
    rp[0] = make_float4(outv[0], outv[1], outv[2], outv[3]);
    rp[1] = make_float4(outv[4], outv[5], outv[6], outv[7]);
    rp[2] = make_float4(outv[8], outv[9], outv[10], outv[11]);
    rp[3] = make_float4(outv[12], outv[13], outv[14], outv[15]);
  }
}

// ---------------- K2: MLP. Block = 64 batches x 4 waves. -------------------
// Wave p computes output slice [16p, 16p+16) of every layer (weights stay
// wave-uniform -> SGPR s_load stream, 4x less per wave than batch-per-thread
// and 4x the occupancy). Activations exchanged via LDS, stride 65 floats so
// lane r / r+32 is the only aliasing (2-way = free).
#define HSTR 65
__global__ __launch_bounds__(256, 3) void mlp_kernel(const float* __restrict__ res,
                                                     const float* __restrict__ obs,
                                                     const float* __restrict__ wb,
                                                     float* __restrict__ out) {
  __shared__ float hx[64 * HSTR];
  const int lane = threadIdx.x & 63;                                  // batch within block
  const int p    = __builtin_amdgcn_readfirstlane(threadIdx.x >> 6);  // wave = out-slice
  const int b    = blockIdx.x * 64 + lane;
  const int ob0  = p * 16;

  const float4* rp = (const float4*)(res + (size_t)b * 16);
  float4 r0 = rp[0], r1 = rp[1], r2 = rp[2], r3 = rp[3];
  const float4* op = (const float4*)(obs + (size_t)b * 16);
  float4 o0 = op[0], o1 = op[1], o2 = op[2], o3 = op[3];
  float rm[8] = {r0.x,r0.y,r0.z,r0.w, r1.x,r1.y,r1.z,r1.w};
  float ag[8] = {r2.x,r2.y,r2.z,r2.w, r3.x,r3.y,r3.z,r3.w};
  float ob[16] = {o0.x,o0.y,o0.z,o0.w, o1.x,o1.y,o1.z,o1.w,
                  o2.x,o2.y,o2.z,o2.w, o3.x,o3.y,o3.z,o3.w};

  float acc[16];
  // ---- layer 1 (folded): slice of 64 outputs ----
  #pragma unroll
  for (int i = 0; i < 16; i++) acc[i] = wb[OFF_BF1P + ob0 + i];
  #pragma unroll
  for (int j = 0; j < 8; j++)
    #pragma unroll
    for (int i = 0; i < 16; i++) acc[i] = fmaf(rm[j], wb[OFF_A + j*64 + ob0 + i], acc[i]);
  #pragma unroll
  for (int j = 0; j < 8; j++)
    #pragma unroll
    for (int i = 0; i < 16; i++) acc[i] = fmaf(ag[j], wb[OFF_C + j*64 + ob0 + i], acc[i]);
  #pragma unroll
  for (int j = 0; j < 16; j++)
    #pragma unroll
    for (int i = 0; i < 16; i++) acc[i] = fmaf(ob[j], wb[OFF_W1B + j*64 + ob0 + i], acc[i]);
  #pragma unroll
  for (int i = 0; i < 16; i++) hx[lane*HSTR + ob0 + i] = fmaxf(acc[i], 0.f);
  __syncthreads();
  float h[64];
  #pragma unroll
  for (int k = 0; k < 64; k++) h[k] = hx[lane*HSTR + k];
  __syncthreads();

  // ---- layer 2 ----
  #pragma unroll
  for (int i = 0; i < 16; i++) acc[i] = wb[OFF_BF2 + ob0 + i];
  #pragma unroll
  for (int k = 0; k < 64; k++)
    #pragma unroll
    for (int i = 0; i < 16; i++) acc[i] = fmaf(h[k], wb[OFF_W2 + k*64 + ob0 + i], acc[i]);
  #pragma unroll
  for (int i = 0; i < 16; i++) hx[lane*HSTR + ob0 + i] = fmaxf(acc[i], 0.f);
  __syncthreads();
  #pragma unroll
  for (int k = 0; k < 64; k++) h[k] = hx[lane*HSTR + k];
  __syncthreads();

  // ---- layer 3 ----
  #pragma unroll
  for (int i = 0; i < 16; i++) acc[i] = wb[OFF_BF3 + ob0 + i];
  #pragma unroll
  for (int k = 0; k < 64; k++)
    #pragma unroll
    for (int i = 0; i < 16; i++) acc[i] = fmaf(h[k], wb[OFF_W3 + k*64 + ob0 + i], acc[i]);
  #pragma unroll
  for (int i = 0; i < 16; i++) hx[lane*HSTR + ob0 + i] = fmaxf(acc[i], 0.f);
  __syncthreads();

  // ---- layer 4 (only wave 0 needed) ----
  if (p == 0) {
    #pragma unroll
    for (int k = 0; k < 64; k++) h[k] = hx[lane*HSTR + k];
    float o4[4];
    #pragma unroll
    for (int d = 0; d < 4; d++) o4[d] = wb[OFF_BF4 + d];
    #pragma unroll
    for (int k = 0; k < 64; k++)
      #pragma unroll
      for (int d = 0; d < 4; d++) o4[d] = fmaf(h[k], wb[OFF_W4 + k*4 + d], o4[d]);
    #pragma unroll
    for (int d = 0; d < 4; d++) o4[d] = fast_tanh(o4[d]);
    ((float4*)out)[b] = make_float4(o4[0], o4[1], o4[2], o4[3]);
  }
}

extern "C" void kernel_launch(void* const* d_in, const int* in_sizes, int n_in,
                              void* d_out, int out_size, void* d_ws, size_t ws_size,
                              hipStream_t stream) {
  const float* x   = (const float*)d_in[0];
  const float* obs = (const float*)d_in[1];
  // d_in[2..4] = src/dst/node_seg: fixed star graph, structure exploited directly
  const float* Wp1 = (const float*)d_in[5];
  const float* bp1 = (const float*)d_in[6];
  const float* Ws1 = (const float*)d_in[7];
  const float* Wn1 = (const float*)d_in[8];
  const float* bc1 = (const float*)d_in[9];
  const float* Wp2 = (const float*)d_in[10];
  const float* bp2 = (const float*)d_in[11];
  const float* Ws2 = (const float*)d_in[12];
  const float* Wn2 = (const float*)d_in[13];
  const float* bc2 = (const float*)d_in[14];
  const float* W1  = (const float*)d_in[15];
  const float* bf1 = (const float*)d_in[16];
  const float* W2  = (const float*)d_in[17];
  const float* bf2 = (const float*)d_in[18];
  const float* W3  = (const float*)d_in[19];
  const float* bf3 = (const float*)d_in[20];
  const float* W4  = (const float*)d_in[21];
  const float* bf4 = (const float*)d_in[22];

  float* blob = (float*)d_ws;
  float* res  = (float*)d_ws + RES_OFF;
  float* out  = (float*)d_out;

  hipLaunchKernelGGL(setup_blob, dim3(1), dim3(256), 0, stream,
                     Wp1, bp1, Ws1, Wn1, bc1, Wp2, bp2, Ws2, Wn2, bc2,
                     W1, bf1, W2, bf2, W3, bf3, W4, bf4, blob);
  hipLaunchKernelGGL(conv_kernel, dim3(8192), dim3(256), 0, stream, x, blob, res);
  hipLaunchKernelGGL(mlp_kernel, dim3(1024), dim3(256), 0, stream, res, obs, blob, out);
}